// Round 7
// baseline (1349.722 us; speedup 1.0000x reference)
//
#include <hip/hip_runtime.h>
#include <hip/hip_bf16.h>
#include <math.h>

// MoEGate: scores = sigmoid(x @ W^T); group top-2-sum -> top-4 groups -> top-8
// experts -> normalized weights * 2.5.
// Phase 1: fp32 vector GEMM (no fp32 MFMA on CDNA4), KSPLIT=7, partials in ws.
//   R6 post-mortem: `#pragma unroll 1` bodies let the RA trade registers for
//   LDS re-reads (VGPR 44-80, VALUBusy half-wasted on non-FMA). Fully
//   unrolled tile body (R1-style) forces honest allocation (VGPR ~132).
//   8x8/lane micro-tile = LDS-optimal (0.0625 b128/FMA): per wave-K-tile
//   64 ds_read_b128 + 8 writes ~= 864 LDS-pipe cyc vs 2048 FMA cyc; LDS pipe
//   (1/CU, shared by 4 SIMDs) floors this structure at ~323 us.
//   Live set: acc 64 + prefetch 32 + av 32 + bv 4 + addr ~12 = ~144 VGPR ->
//   3 waves/EU, 12 waves/CU (grid 3584 = 14 blocks/CU demanded, LDS 120 KB).
// Phase 2: one WAVE per token, register-resident scores, shuffle reductions.

constexpr int T_TOK = 8192;
constexpr int HID   = 7168;
constexpr int NEXP  = 256;

constexpr int BM = 64, BN = 64, BK = 16;
constexpr int KSPLIT = 7;
constexpr int KHALF  = HID / KSPLIT;   // 1024 -> 64 K-tiles of 16
constexpr int LDS4   = 5;              // float4 stride (4 data + 1 pad):
                                       // fragment reads hit all 32 banks once
                                       // (ty*20 mod 32 = {0,20,8,28,16,4,24,12},
                                       // each b128 spans 4 banks -> full cover)

__global__ __launch_bounds__(64)
void gemm_partial(const float* __restrict__ x, const float* __restrict__ w,
                  float* __restrict__ part) {
  __shared__ float4 As4[BM * LDS4];
  __shared__ float4 Bs4[BN * LDS4];
  const int lane = threadIdx.x;
  const int e0 = blockIdx.x * BN;     // expert tile
  const int t0 = blockIdx.y * BM;     // token tile
  const int kp = blockIdx.z;          // k-split slice
  const size_t kbase = (size_t)kp * KHALF;

  // compute mapping: 8x8 micro-tile per lane
  const int tx = lane & 7;            // expert sub
  const int ty = lane >> 3;           // token sub
  // staging mapping: 16 rows x 4 float4-cols per pass, 4 passes
  const int sc = lane & 3;
  const int sr = lane >> 2;

  float acc[8][8];
#pragma unroll
  for (int i = 0; i < 8; ++i)
#pragma unroll
    for (int j = 0; j < 8; ++j) acc[i][j] = 0.f;

  const float* xs = x + (size_t)(t0 + sr) * HID + kbase + 4 * sc;
  const float* wsrc = w + (size_t)(e0 + sr) * HID + kbase + 4 * sc;

  float4 ta[4], tb[4];
#pragma unroll
  for (int p = 0; p < 4; ++p) {
    ta[p] = *(const float4*)(xs + (size_t)(16 * p) * HID);
    tb[p] = *(const float4*)(wsrc + (size_t)(16 * p) * HID);
  }

  for (int k0 = 0; k0 < KHALF; k0 += BK) {
    __syncthreads();
#pragma unroll
    for (int p = 0; p < 4; ++p) {
      As4[(sr + 16 * p) * LDS4 + sc] = ta[p];
      Bs4[(sr + 16 * p) * LDS4 + sc] = tb[p];
    }
    __syncthreads();
    if (k0 + BK < KHALF) {
#pragma unroll
      for (int p = 0; p < 4; ++p) {
        ta[p] = *(const float4*)(xs + (size_t)(16 * p) * HID + (k0 + BK));
        tb[p] = *(const float4*)(wsrc + (size_t)(16 * p) * HID + (k0 + BK));
      }
    }
    // fully unrolled tile body: 64 ds_read_b128 (immediate offsets) + 1024 FMA
#pragma unroll
    for (int q = 0; q < 4; ++q) {
      float4 av[8];
#pragma unroll
      for (int i = 0; i < 8; ++i) av[i] = As4[(ty + 8 * i) * LDS4 + q];
#pragma unroll
      for (int j = 0; j < 8; ++j) {
        const float4 bv = Bs4[(tx + 8 * j) * LDS4 + q];
#pragma unroll
        for (int i = 0; i < 8; ++i) {
          acc[i][j] = fmaf(av[i].x, bv.x, acc[i][j]);
          acc[i][j] = fmaf(av[i].y, bv.y, acc[i][j]);
          acc[i][j] = fmaf(av[i].z, bv.z, acc[i][j]);
          acc[i][j] = fmaf(av[i].w, bv.w, acc[i][j]);
        }
      }
    }
  }

  float* pout = part + (size_t)kp * T_TOK * NEXP;
#pragma unroll
  for (int i = 0; i < 8; ++i) {
    const size_t t = t0 + ty + 8 * i;
#pragma unroll
    for (int j = 0; j < 8; ++j)
      pout[t * NEXP + (e0 + tx + 8 * j)] = acc[i][j];
  }
}

// one wave per token; lane l owns experts 4l..4l+3 entirely in registers
__global__ __launch_bounds__(256)
void routing_kernel(const float* __restrict__ part,
                    const float* __restrict__ bias,
                    float* __restrict__ out) {
  const int lane = threadIdx.x & 63;
  const int t = blockIdx.x * 4 + (threadIdx.x >> 6);
  const int e_base = 4 * lane;

  // reduce K-split partials, sigmoid, add bias
  float4 z = make_float4(0.f, 0.f, 0.f, 0.f);
#pragma unroll
  for (int kp = 0; kp < KSPLIT; ++kp) {
    float4 v = *(const float4*)(part + (size_t)kp * T_TOK * NEXP +
                                (size_t)t * NEXP + e_base);
    z.x += v.x; z.y += v.y; z.z += v.z; z.w += v.w;
  }
  float s[4], sb[4];
  const float4 b4 = *(const float4*)(bias + e_base);
  s[0] = 1.f / (1.f + expf(-z.x)); sb[0] = s[0] + b4.x;
  s[1] = 1.f / (1.f + expf(-z.y)); sb[1] = s[1] + b4.y;
  s[2] = 1.f / (1.f + expf(-z.z)); sb[2] = s[2] + b4.z;
  s[3] = 1.f / (1.f + expf(-z.w)); sb[3] = s[3] + b4.w;

  // lane-local top-2 of 4 (pairwise tournament):
  //   second-max = max( min(Ma,Mb), max(ma,mb) )  [m_loser <= min(Ma,Mb)]
  const float Ma = fmaxf(sb[0], sb[1]), ma = fminf(sb[0], sb[1]);
  const float Mb = fmaxf(sb[2], sb[3]), mb = fminf(sb[2], sb[3]);
  float m1 = fmaxf(Ma, Mb);
  float m2 = fmaxf(fminf(Ma, Mb), fmaxf(ma, mb));
  // merge (m1,m2) pairs across the 8 lanes of the group via shfl_xor 1,2,4
#pragma unroll
  for (int off = 1; off < 8; off <<= 1) {
    const float o1 = __shfl_xor(m1, off);
    const float o2 = __shfl_xor(m2, off);
    const float n1 = fmaxf(m1, o1);
    m2 = fmaxf(fminf(m1, o1), fmaxf(m2, o2));
    m1 = n1;
  }
  const float gsum = m1 + m2;   // identical across the 8 lanes of each group

  // all 8 group sums to every lane
  float gs[8];
#pragma unroll
  for (int g = 0; g < 8; ++g) gs[g] = __shfl(gsum, g * 8);

  // stable top-4 groups (strict >, ascending scan -> lowest index on ties)
  unsigned gmask = 0;
#pragma unroll
  for (int r = 0; r < 4; ++r) {
    int best = 0; float bv = -3.4e38f;
#pragma unroll
    for (int g = 0; g < 8; ++g) {
      const bool ok = (((gmask >> g) & 1u) == 0) && (gs[g] > bv);
      bv = ok ? gs[g] : bv;
      best = ok ? g : best;
    }
    gmask |= 1u << best;
  }

  // mask out unselected groups
  const bool sel = (gmask >> (lane >> 3)) & 1u;
#pragma unroll
  for (int j = 0; j < 4; ++j) sb[j] = sel ? sb[j] : -3.4e38f;

  // top-8 experts: 8 rounds of wave-argmax (ties -> lowest expert index)
  float wq[8]; float iq[8];
#pragma unroll
  for (int r = 0; r < 8; ++r) {
    float bv = sb[0]; int bi = e_base; float bs = s[0];
#pragma unroll
    for (int j = 1; j < 4; ++j) {
      const bool c = sb[j] > bv;
      bv = c ? sb[j] : bv; bi = c ? e_base + j : bi; bs = c ? s[j] : bs;
    }
#pragma unroll
    for (int off = 1; off < 64; off <<= 1) {
      const float ov = __shfl_xor(bv, off);
      const int   oi = __shfl_xor(bi, off);
      const float os = __shfl_xor(bs, off);
      const bool take = (ov > bv) || (ov == bv && oi < bi);
      bv = take ? ov : bv; bi = take ? oi : bi; bs = take ? os : bs;
    }
    wq[r] = bs; iq[r] = (float)bi;
#pragma unroll
    for (int j = 0; j < 4; ++j)
      if (e_base + j == bi) sb[j] = -3.4e38f;
  }

  float wsum = 1e-20f;
#pragma unroll
  for (int r = 0; r < 8; ++r) wsum += wq[r];
  const float scale = 2.5f / wsum;

  if (lane == 0) {
    float4* ow = (float4*)(out + (size_t)t * 8);
    ow[0] = make_float4(wq[0] * scale, wq[1] * scale, wq[2] * scale, wq[3] * scale);
    ow[1] = make_float4(wq[4] * scale, wq[5] * scale, wq[6] * scale, wq[7] * scale);
    float4* oi = (float4*)(out + (size_t)T_TOK * 8 + (size_t)t * 8);
    oi[0] = make_float4(iq[0], iq[1], iq[2], iq[3]);
    oi[1] = make_float4(iq[4], iq[5], iq[6], iq[7]);
  }
}

extern "C" void kernel_launch(void* const* d_in, const int* in_sizes, int n_in,
                              void* d_out, int out_size, void* d_ws, size_t ws_size,
                              hipStream_t stream) {
  const float* x    = (const float*)d_in[0];
  const float* w    = (const float*)d_in[1];
  const float* bias = (const float*)d_in[2];
  float* out  = (float*)d_out;
  float* part = (float*)d_ws;   // [KSPLIT][T_TOK][NEXP] fp32 = 57.3 MB

  dim3 ggrid(NEXP / BN, T_TOK / BM, KSPLIT);   // (4, 128, 7) = 3584 blocks
  hipLaunchKernelGGL(gemm_partial, ggrid, dim3(64), 0, stream, x, w, part);
  hipLaunchKernelGGL(routing_kernel, dim3(T_TOK / 4), dim3(256), 0, stream,
                     part, bias, out);
}